// Round 10
// baseline (165.630 us; speedup 1.0000x reference)
//
#include <hip/hip_runtime.h>
#include <hip/hip_bf16.h>

// out[4096,1000] = core[4096,4096] @ weights[1000,4096]^T, fp32.
// R8: f16 GEMM + partials-epilogue (proven R7). Lever: KSPLIT 2->4 enabled by
//     f16 partial buffers (ws fit: 32+8+32=72 MiB). 1024 blocks = 4 blocks/CU
//     -> barrier-drain overlap (m114/m103 mechanism). K-loop/swizzle unchanged.

#define M_DIM 4096
#define K_DIM 4096
#define N_CLS 1000
#define N_PAD 1024

#define BM 128
#define BN 128
#define BK 32
#define KSPLIT 4

typedef _Float16 f16x8 __attribute__((ext_vector_type(8)));
typedef _Float16 f16x4 __attribute__((ext_vector_type(4)));
typedef float f32x4 __attribute__((ext_vector_type(4)));

// ---------- fp32 -> f16 convert (core + padded weights), grid-stride ----------
__global__ void convert_f16(const float* __restrict__ core,
                            const float* __restrict__ wts,
                            _Float16* __restrict__ A16,
                            _Float16* __restrict__ W16,
                            int na8, int nw8, int w_src) {
    int total = na8 + nw8;
    for (int i = blockIdx.x * blockDim.x + threadIdx.x; i < total;
         i += gridDim.x * blockDim.x) {
        const float* src;
        _Float16* dst;
        bool valid;
        if (i < na8) {
            src = core + (size_t)i * 8;
            dst = A16 + (size_t)i * 8;
            valid = true;
        } else {
            int j = i - na8;
            src = wts + (size_t)j * 8;
            dst = W16 + (size_t)j * 8;
            valid = (j * 8 < w_src);   // w_src % 8 == 0
        }
        float f[8] = {0, 0, 0, 0, 0, 0, 0, 0};
        if (valid) {
            float4 v0 = ((const float4*)src)[0];
            float4 v1 = ((const float4*)src)[1];
            f[0] = v0.x; f[1] = v0.y; f[2] = v0.z; f[3] = v0.w;
            f[4] = v1.x; f[5] = v1.y; f[6] = v1.z; f[7] = v1.w;
        }
        f16x8 h;
#pragma unroll
        for (int j = 0; j < 8; ++j) h[j] = (_Float16)f[j];   // fptrunc = RNE
        *(f16x8*)dst = h;
    }
}

// ---------- async global->LDS, width 16 (literal) ----------
__device__ inline void load_lds16(const _Float16* g, _Float16* l) {
    __builtin_amdgcn_global_load_lds(
        (const __attribute__((address_space(1))) unsigned int*)(const void*)g,
        (__attribute__((address_space(3))) unsigned int*)(void*)l, 16, 0, 0);
}

// ---------- f16 GEMM, 128x128 tile, dbuf 2ph, swizzled LDS, split-K x4 ----------
// LDS row r (128B): logical chunks 0-3 = A row r k-window, 4-7 = B row r.
// Physical slot = chunk ^ (r&7); written via pre-swizzled global SOURCE
// (linear global_load_lds dest), read with same XOR. Measured 0 conflicts (R3/R6/R7).
// Epilogue: f16 partials to P[ks][4096][1024] (plain stores, no atomics).
__launch_bounds__(256, 4)
__global__ void gemm_f16_kernel(const _Float16* __restrict__ A16,
                                const _Float16* __restrict__ W16,
                                _Float16* __restrict__ P) {
    __shared__ __align__(16) _Float16 sAB[2][BM * 64];   // 2 x 16 KB

    const int tid  = threadIdx.x;
    const int lane = tid & 63;
    const int wid  = tid >> 6;
    const int wr   = wid >> 1;   // 0..1 (row half)
    const int wc   = wid & 1;    // 0..1 (col half)

    // XCD-chunked bijective swizzle: 1024 blocks, 128 consecutive per XCD.
    int bid = blockIdx.x;
    int swz = (bid & 7) * 128 + (bid >> 3);
    const int colb = swz & 7;          // 8 col-blocks (fastest -> A-panel L2 reuse)
    const int ks   = (swz >> 3) & 3;   // 4 K-slices
    const int rowb = swz >> 5;         // 32 row-blocks
    const int brow = rowb * BM;
    const int bcol = colb * BN;
    const int kbeg = ks * (K_DIM / KSPLIT);
    const int NT   = (K_DIM / KSPLIT) / BK;   // 32 K-steps

    // Staging: 1024 16B chunks per K-step tile, 4 per thread. Dest LINEAR,
    // source pre-swizzled.
    const _Float16* src[4];
    int dstOff[4];
#pragma unroll
    for (int i = 0; i < 4; ++i) {
        int s = tid + 256 * i;          // slot 0..1023
        int r = s >> 3;                 // row 0..127
        int clog = (s & 7) ^ (r & 7);   // logical chunk stored at this slot
        dstOff[i] = s * 8;              // f16 offset (16B chunks)
        if (clog < 4)
            src[i] = A16 + (size_t)(brow + r) * K_DIM + kbeg + clog * 8;
        else
            src[i] = W16 + (size_t)(bcol + r) * K_DIM + kbeg + (clog - 4) * 8;
    }

    f32x4 acc[4][4] = {};

    // read-side swizzle: frag rows have row&7 == lr&7 (m*16, wr*64 are 0 mod 8)
    const int lr = lane & 15;
    const int hk = lane >> 4;                  // k-chunk 0..3
    const int xa = (hk ^ (lr & 7)) * 8;        // A chunk slot offset (f16)
    const int xb = xa ^ 32;                    // B: logical chunk |4 -> slot^4

#define STAGE(buf, koff)                                        \
    {                                                           \
        _Pragma("unroll")                                       \
        for (int i = 0; i < 4; ++i)                             \
            load_lds16(src[i] + (koff), &sAB[buf][dstOff[i]]);  \
    }

    STAGE(0, 0);
    __syncthreads();
    int cur = 0;

    for (int t = 0; t < NT; ++t) {
        if (t + 1 < NT) STAGE(cur ^ 1, (t + 1) * BK);

        f16x8 a[4], b[4];
#pragma unroll
        for (int m = 0; m < 4; ++m) {
            int r = wr * 64 + m * 16 + lr;
            a[m] = *(const f16x8*)&sAB[cur][r * 64 + xa];
        }
#pragma unroll
        for (int n = 0; n < 4; ++n) {
            int r = wc * 64 + n * 16 + lr;
            b[n] = *(const f16x8*)&sAB[cur][r * 64 + xb];
        }

#pragma unroll
        for (int m = 0; m < 4; ++m)
#pragma unroll
            for (int n = 0; n < 4; ++n)
                acc[m][n] = __builtin_amdgcn_mfma_f32_16x16x32_f16(a[m], b[n], acc[m][n], 0, 0, 0);

        __syncthreads();
        cur ^= 1;
    }

    // Epilogue: C/D layout col=lane&15, row=(lane>>4)*4+j.
    // f16 partials, plain stores (lanes 0-15 consecutive cols -> 32B segments).
    _Float16* Pk = P + (size_t)ks * M_DIM * N_PAD;
#pragma unroll
    for (int m = 0; m < 4; ++m) {
        int r0 = brow + wr * 64 + m * 16 + hk * 4;
#pragma unroll
        for (int n = 0; n < 4; ++n) {
            int c = bcol + wc * 64 + n * 16 + lr;
#pragma unroll
            for (int j = 0; j < 4; ++j)
                Pk[(size_t)(r0 + j) * N_PAD + c] = (_Float16)acc[m][n][j];
        }
    }
#undef STAGE
}

// ---------- reduce: out[4096][1000] = sum of 4 f16 slices (strip pad) --------
__global__ void reduce_kernel(const _Float16* __restrict__ P,
                              float* __restrict__ out, int n4out) {
    int i = blockIdx.x * blockDim.x + threadIdx.x;
    if (i >= n4out) return;
    int flat = i * 4;
    int row = flat / N_CLS;            // 1000 % 4 == 0 -> 4 elems in one row
    int col = flat - row * N_CLS;      // col % 4 == 0 -> 8B-aligned f16x4
    size_t p = (size_t)row * N_PAD + col;
    float s0 = 0.f, s1 = 0.f, s2 = 0.f, s3 = 0.f;
#pragma unroll
    for (int s = 0; s < KSPLIT; ++s) {
        f16x4 v = *(const f16x4*)&P[(size_t)s * M_DIM * N_PAD + p];
        s0 += (float)v[0]; s1 += (float)v[1];
        s2 += (float)v[2]; s3 += (float)v[3];
    }
    float4 r; r.x = s0; r.y = s1; r.z = s2; r.w = s3;
    *(float4*)&out[flat] = r;
}

// ---------- fp32 fallback (only if ws too small) ----------
__global__ void fallback_gemm(const float* __restrict__ A, const float* __restrict__ W,
                              float* __restrict__ out) {
    __shared__ float sA[16][17];
    __shared__ float sW[16][17];
    int tx = threadIdx.x, ty = threadIdx.y;
    int row  = blockIdx.y * 16 + ty;
    int wrow = blockIdx.x * 16 + ty;
    float acc = 0.f;
    for (int k0 = 0; k0 < K_DIM; k0 += 16) {
        sA[ty][tx] = A[(size_t)row * K_DIM + k0 + tx];
        sW[ty][tx] = (wrow < N_CLS) ? W[(size_t)wrow * K_DIM + k0 + tx] : 0.f;
        __syncthreads();
#pragma unroll
        for (int kk = 0; kk < 16; ++kk) acc += sA[ty][kk] * sW[tx][kk];
        __syncthreads();
    }
    int col = blockIdx.x * 16 + tx;
    if (col < N_CLS) out[(size_t)row * N_CLS + col] = acc;
}

extern "C" void kernel_launch(void* const* d_in, const int* in_sizes, int n_in,
                              void* d_out, int out_size, void* d_ws, size_t ws_size,
                              hipStream_t stream) {
    const float* core    = (const float*)d_in[0];   // [4096][4096]
    const float* weights = (const float*)d_in[1];   // [1000][4096]
    float* out = (float*)d_out;                     // [4096][1000]

    const size_t A_ELEMS = (size_t)M_DIM * K_DIM;   // 16,777,216
    const size_t W_SRC   = (size_t)N_CLS * K_DIM;   //  4,096,000
    const size_t W_ELEMS = (size_t)N_PAD * K_DIM;   //  4,194,304
    const size_t P_ELEMS = (size_t)KSPLIT * M_DIM * N_PAD;   // 16,777,216 f16
    const size_t need = (A_ELEMS + W_ELEMS + P_ELEMS) * sizeof(_Float16); // 72 MiB

    if (ws_size < need) {
        dim3 blk(16, 16), grd((N_CLS + 15) / 16, M_DIM / 16);
        fallback_gemm<<<grd, blk, 0, stream>>>(core, weights, out);
        return;
    }

    _Float16* A16 = (_Float16*)d_ws;
    _Float16* W16 = A16 + A_ELEMS;
    _Float16* P   = W16 + W_ELEMS;

    // 1) convert both inputs to f16 (weights padded to 1024 rows with zeros)
    int na8 = (int)(A_ELEMS / 8);                    // 2,097,152
    int nw8 = (int)(W_ELEMS / 8);                    //   524,288
    convert_f16<<<2048, 256, 0, stream>>>(core, weights, A16, W16,
                                          na8, nw8, (int)W_SRC);

    // 2) GEMM: 1024 blocks = (8 col) x (32 row) x (4 k-slices), 4 blocks/CU.
    gemm_f16_kernel<<<(N_PAD / BN) * (M_DIM / BM) * KSPLIT, 256, 0, stream>>>(
        A16, W16, P);

    // 3) reduce the 4 f16 K-slices into out (strips the 1024->1000 col pad)
    int n4out = (M_DIM * N_CLS) / 4;                 // 1,024,000
    reduce_kernel<<<(n4out + 255) / 256, 256, 0, stream>>>(P, out, n4out);
}